// Round 4
// baseline (6713.570 us; speedup 1.0000x reference)
//
#include <hip/hip_runtime.h>
#include <math.h>

// POSTagEncoder: expert-routed linear -> 1-layer LSTM (i,f,g,o) -> time max-pool.
// S=8192, D=128, E=48. Output [1,128] fp32.
//
// Round-4 scan design: MFMA-based. Rounds 2-3 proved the register allocator will
// not keep 128 VALU-addressable weight VGPRs live across the 8192-step loop
// (VGPR_Count stuck at ~104, ~570 instr/step of reload traffic). MFMA sidesteps
// this: A/B operands read DIRECTLY from AGPRs, so W_hh lives as 32 MFMA
// A-fragments/thread (8 row-tiles x 4 K-chunks, fp16, 128 regs -> AGPR file).
// Per step: h broadcast via LDS as B-fragments with all 16 columns identical
// (robust to column mapping), 32 mfma_16x16x32_f16, pre-activations exchanged
// through LDS (col-0 lanes write), 128 update lanes (32 per wave) do the
// nonlinear update. Two barriers/step.

#define SEQ   8192
#define DIM   128
#define NGATE 512
#define NEXP  48

typedef _Float16 v8h  __attribute__((ext_vector_type(8)));
typedef float    v4f  __attribute__((ext_vector_type(4)));

__device__ __forceinline__ float sigm_fast(float x) {
    return __fdividef(1.0f, 1.0f + __expf(-x));   // inf-safe both ends
}
__device__ __forceinline__ float tanh_fast(float x) {
    float e = __expf(2.0f * x);
    return 1.0f - __fdividef(2.0f, e + 1.0f);     // +-1 at saturation
}
__device__ __forceinline__ v8h pack8(float4 a, float4 b) {   // RNE converts
    v8h r;
    r[0]=(_Float16)a.x; r[1]=(_Float16)a.y; r[2]=(_Float16)a.z; r[3]=(_Float16)a.w;
    r[4]=(_Float16)b.x; r[5]=(_Float16)b.y; r[6]=(_Float16)b.z; r[7]=(_Float16)b.w;
    return r;
}

// ---------------------------------------------------------------------------
// K1a: z[s] = W_exp[pos_ids[s]] @ embs[s] + b_exp  -> xg[s*512 + 0..128)
// ---------------------------------------------------------------------------
__global__ __launch_bounds__(64) void expert_gemv(
    const float* __restrict__ embs, const int* __restrict__ pos_ids,
    const float* __restrict__ W_exp, const float* __restrict__ b_exp,
    float* __restrict__ xg)
{
    __shared__ float Wl[DIM * DIM];          // 64KB, rows XOR-swizzled
    const int e     = blockIdx.x % NEXP;
    const int slice = blockIdx.x / NEXP;     // 0..7
    const int tid   = threadIdx.x;           // 0..63

    const float4* Wg = (const float4*)(W_exp + (size_t)e * DIM * DIM);
    #pragma unroll 4
    for (int it = 0; it < 64; ++it) {
        int idx = it * 64 + tid;             // 0..4095 float4s
        int r = idx >> 5, c4 = idx & 31;
        float4 v = Wg[idx];
        *(float4*)&Wl[r * DIM + (((c4 ^ (r & 31))) << 2)] = v;
    }
    const float b0 = b_exp[e * DIM + tid];
    const float b1 = b_exp[e * DIM + 64 + tid];
    __syncthreads();

    const int r0 = tid, r1 = tid + 64;
    const int sw0 = r0 & 31, sw1 = r1 & 31;
    const int sBeg = slice * 1024, sEnd = sBeg + 1024;
    for (int base = sBeg; base < sEnd; base += 64) {
        int pid = pos_ids[base + tid];
        unsigned long long m = __ballot(pid == e);
        while (m) {
            int t = __builtin_ctzll(m);
            m &= m - 1;
            int s = base + t;
            const float4* ev = (const float4*)(embs + (size_t)s * DIM);
            float a0 = b0, a1 = b1;
            #pragma unroll
            for (int j4 = 0; j4 < 32; ++j4) {
                float4 x  = ev[j4];
                float4 w0 = *(const float4*)&Wl[r0 * DIM + ((j4 ^ sw0) << 2)];
                float4 w1 = *(const float4*)&Wl[r1 * DIM + ((j4 ^ sw1) << 2)];
                a0 = fmaf(w0.x,x.x,fmaf(w0.y,x.y,fmaf(w0.z,x.z,fmaf(w0.w,x.w,a0))));
                a1 = fmaf(w1.x,x.x,fmaf(w1.y,x.y,fmaf(w1.z,x.z,fmaf(w1.w,x.w,a1))));
            }
            float* zp = xg + (size_t)s * NGATE;
            zp[tid]      = a0;
            zp[tid + 64] = a1;
        }
    }
}

// ---------------------------------------------------------------------------
// K1b: xg[s] = W_ih @ z[s] + b_ih + b_hh   (z read from xg[s*512+0..128))
// ---------------------------------------------------------------------------
__global__ __launch_bounds__(256) void gate_gemm(
    const float* __restrict__ W_ih, const float* __restrict__ b_ih,
    const float* __restrict__ b_hh, float* __restrict__ xg)
{
    __shared__ float zl[32 * DIM];    // 16KB
    __shared__ float Wl[64 * DIM];    // 32KB
    const int tid = threadIdx.x;
    const int s0  = blockIdx.x * 32;

    #pragma unroll
    for (int it = 0; it < 4; ++it) {
        int idx = it * 256 + tid;
        int tok = idx >> 5, c4 = idx & 31;
        float4 v = *(const float4*)(xg + ((size_t)(s0 + tok)) * NGATE + (c4 << 2));
        *(float4*)&zl[tok * DIM + (((c4 ^ (tok & 31))) << 2)] = v;
    }
    __syncthreads();

    const int lane = tid & 63;
    const int tg   = tid >> 6;
    const int swr  = lane & 31;

    for (int ch = 0; ch < 8; ++ch) {
        #pragma unroll
        for (int it = 0; it < 8; ++it) {
            int idx = it * 256 + tid;
            int r = idx >> 5, c4 = idx & 31;
            float4 v = *(const float4*)(W_ih + ((size_t)(ch * 64 + r)) * DIM + (c4 << 2));
            *(float4*)&Wl[r * DIM + ((c4 ^ (r & 31)) << 2)] = v;
        }
        __syncthreads();

        const int row = ch * 64 + lane;
        const float bias = b_ih[row] + b_hh[row];
        float acc[8];
        #pragma unroll
        for (int k = 0; k < 8; ++k) acc[k] = bias;
        #pragma unroll 8
        for (int j4 = 0; j4 < 32; ++j4) {
            float4 w = *(const float4*)&Wl[lane * DIM + ((j4 ^ swr) << 2)];
            #pragma unroll
            for (int k = 0; k < 8; ++k) {
                int tok = tg * 8 + k;
                float4 z = *(const float4*)&zl[tok * DIM + ((j4 ^ (tok & 31)) << 2)];
                acc[k] = fmaf(w.x,z.x,fmaf(w.y,z.y,fmaf(w.z,z.z,fmaf(w.w,z.w,acc[k]))));
            }
        }
        #pragma unroll
        for (int k = 0; k < 8; ++k) {
            int tok = tg * 8 + k;
            xg[((size_t)(s0 + tok)) * NGATE + row] = acc[k];
        }
        __syncthreads();
    }
}

// ---------------------------------------------------------------------------
// K2: MFMA LSTM scan + max-pool. ONE block, 256 threads (4 waves, 1 wave/SIMD).
// Wave w computes gate w's 128 pre-activation rows via 8 tiles x 4 K-chunks of
// mfma_f32_16x16x32_f16. A-fragment layout: A[m=lane&15][k=(lane>>4)*8+j].
// B built with ALL 16 columns = h  => every output column equals W_hh@h.
// C layout: col=lane&15, row=(lane>>4)*4+reg  => col-0 lanes (0,16,32,48) hold
// each tile's 16 rows as 4x float4 -> one ds_write_b128 per tile.
// ---------------------------------------------------------------------------
__global__ __launch_bounds__(256, 1) void lstm_scan(
    const float* __restrict__ xg, const float* __restrict__ W_hh,
    float* __restrict__ out)
{
    const int T    = threadIdx.x;
    const int g    = T >> 6;        // wave id == gate id (0=i,1=f,2=g,3=o)
    const int lane = T & 63;
    const int q    = lane >> 4;     // quad 0..3
    const int col  = lane & 15;     // C/D column; A row m
    const bool upd = (lane < 32);   // 32 update lanes per wave
    const int d    = g * 32 + (lane & 31);   // hidden dim owned by update lane

    __shared__ __align__(16) _Float16 hbuf[DIM];    // h_t as fp16
    __shared__ __align__(16) float    pre[NGATE];   // W_hh @ h pre-activations

    // ---- W_hh -> 32 A-fragments (fp16, RNE). Named variables, no arrays:
    //      MFMA-only consumers => allocator can park them in AGPRs. ----
    const float* Wb = W_hh + ((size_t)(g * DIM + col)) * DIM + q * 8;
#define LOADA(m,c) v8h a_##m##_##c; { \
        const float4* p = (const float4*)(Wb + (m) * 16 * DIM + (c) * 32); \
        a_##m##_##c = pack8(p[0], p[1]); }
    LOADA(0,0) LOADA(0,1) LOADA(0,2) LOADA(0,3)
    LOADA(1,0) LOADA(1,1) LOADA(1,2) LOADA(1,3)
    LOADA(2,0) LOADA(2,1) LOADA(2,2) LOADA(2,3)
    LOADA(3,0) LOADA(3,1) LOADA(3,2) LOADA(3,3)
    LOADA(4,0) LOADA(4,1) LOADA(4,2) LOADA(4,3)
    LOADA(5,0) LOADA(5,1) LOADA(5,2) LOADA(5,3)
    LOADA(6,0) LOADA(6,1) LOADA(6,2) LOADA(6,3)
    LOADA(7,0) LOADA(7,1) LOADA(7,2) LOADA(7,3)
#undef LOADA

    float cst  = 0.0f;
    float hmax = -INFINITY;
    float xa0 = 0, xa1 = 0, xa2 = 0, xa3 = 0;   // xg[t]   for dim d
    float xb0 = 0, xb1 = 0, xb2 = 0, xb3 = 0;   // xg[t+1]
    if (upd) {
        hbuf[d] = (_Float16)0.0f;               // h_0 = 0
        xa0 = xg[d];                 xa1 = xg[DIM + d];
        xa2 = xg[2 * DIM + d];       xa3 = xg[3 * DIM + d];
        xb0 = xg[NGATE + d];         xb1 = xg[NGATE + DIM + d];
        xb2 = xg[NGATE + 2 * DIM + d]; xb3 = xg[NGATE + 3 * DIM + d];
    }
    __syncthreads();

    const v4f Z4 = {0.0f, 0.0f, 0.0f, 0.0f};

    for (int t = 0; t < SEQ; ++t) {
        // B fragments: all 16 columns identical = h; lane needs h[c*32 + q*8 + j]
        const v8h B0 = *(const v8h*)&hbuf[ 0 + q * 8];
        const v8h B1 = *(const v8h*)&hbuf[32 + q * 8];
        const v8h B2 = *(const v8h*)&hbuf[64 + q * 8];
        const v8h B3 = *(const v8h*)&hbuf[96 + q * 8];

#define TILE(m) v4f acc##m = \
        __builtin_amdgcn_mfma_f32_16x16x32_f16(a_##m##_3, B3, \
        __builtin_amdgcn_mfma_f32_16x16x32_f16(a_##m##_2, B2, \
        __builtin_amdgcn_mfma_f32_16x16x32_f16(a_##m##_1, B1, \
        __builtin_amdgcn_mfma_f32_16x16x32_f16(a_##m##_0, B0, Z4, 0,0,0), 0,0,0), 0,0,0), 0,0,0);
        TILE(0) TILE(1) TILE(2) TILE(3) TILE(4) TILE(5) TILE(6) TILE(7)
#undef TILE

        // col-0 lanes scatter pre-activations: lane (q,0) holds rows m*16+q*4..+3
        if (col == 0) {
            float* pb = &pre[g * DIM + q * 4];
            *(v4f*)(pb +   0) = acc0;  *(v4f*)(pb +  16) = acc1;
            *(v4f*)(pb +  32) = acc2;  *(v4f*)(pb +  48) = acc3;
            *(v4f*)(pb +  64) = acc4;  *(v4f*)(pb +  80) = acc5;
            *(v4f*)(pb +  96) = acc6;  *(v4f*)(pb + 112) = acc7;
        }
        __syncthreads();   // A: pre[] readable

        // prefetch xg[t+2] (distance 2 covers L2/HBM latency)
        const size_t tn = (size_t)((t + 2 < SEQ) ? (t + 2) : (SEQ - 1)) * NGATE;
        float xn0 = 0, xn1 = 0, xn2 = 0, xn3 = 0;
        if (upd) {
            xn0 = xg[tn + d];           xn1 = xg[tn + DIM + d];
            xn2 = xg[tn + 2 * DIM + d]; xn3 = xg[tn + 3 * DIM + d];

            const float pi = pre[d]           + xa0;
            const float pf = pre[DIM + d]     + xa1;
            const float pg = pre[2 * DIM + d] + xa2;
            const float po = pre[3 * DIM + d] + xa3;
            const float iv = sigm_fast(pi);
            const float fv = sigm_fast(pf);
            const float gv = tanh_fast(pg);
            const float ov = sigm_fast(po);
            cst = fmaf(fv, cst, iv * gv);
            const float h = ov * tanh_fast(cst);
            hmax = fmaxf(hmax, h);
            hbuf[d] = (_Float16)h;     // RNE
        }
        xa0 = xb0; xa1 = xb1; xa2 = xb2; xa3 = xb3;
        xb0 = xn0; xb1 = xn1; xb2 = xn2; xb3 = xn3;

        __syncthreads();   // B: hbuf readable for next step's B-fragments
    }

    if (upd) out[d] = hmax;   // out[1][128]
}

// ---------------------------------------------------------------------------
extern "C" void kernel_launch(void* const* d_in, const int* in_sizes, int n_in,
                              void* d_out, int out_size, void* d_ws, size_t ws_size,
                              hipStream_t stream)
{
    const float* embs  = (const float*)d_in[0];
    const int*   pos   = (const int*)  d_in[1];
    const float* W_exp = (const float*)d_in[2];
    const float* b_exp = (const float*)d_in[3];
    const float* W_ih  = (const float*)d_in[4];
    const float* W_hh  = (const float*)d_in[5];
    const float* b_ih  = (const float*)d_in[6];
    const float* b_hh  = (const float*)d_in[7];
    float* out = (float*)d_out;
    float* xg  = (float*)d_ws;   // [SEQ][512] fp32 = 16 MB (z in cols 0..127)

    expert_gemv<<<dim3(NEXP * 8), 64, 0, stream>>>(embs, pos, W_exp, b_exp, xg);
    gate_gemm  <<<dim3(256), 256, 0, stream>>>(W_ih, b_ih, b_hh, xg);
    lstm_scan  <<<dim3(1), 256, 0, stream>>>(xg, W_hh, out);
}

// Round 5
// 5034.082 us; speedup vs baseline: 1.3336x; 1.3336x over previous
//
#include <hip/hip_runtime.h>
#include <math.h>

// POSTagEncoder: expert-routed linear -> 1-layer LSTM (i,f,g,o) -> time max-pool.
// S=8192, D=128, E=48. Output [1,128] fp32.
//
// Round-5 scan: MFMA scan with (a) ONE raw-asm barrier per step (lgkmcnt only --
// __syncthreads' vmcnt(0) drain was killing the xg prefetch, ~1200 cyc/step),
// (b) per-wave dim ownership: wave g computes ALL 4 gates for dims [32g,32g+32),
// so pre-activations never leave the wave (in-register cndmask select from the
// MFMA C-regs -- all 16 C columns are identical because B's columns are all h),
// (c) xg re-laid out as [t][dim][gate] so one global_load_dwordx4 per update
// lane per step, issued at step top with distance-4 rotation (raw barrier keeps
// them in flight).

#define SEQ   8192
#define DIM   128
#define NGATE 512
#define NEXP  48

typedef _Float16 v8h  __attribute__((ext_vector_type(8)));
typedef float    v4f  __attribute__((ext_vector_type(4)));

__device__ __forceinline__ float sigm_fast(float x) {
    return __fdividef(1.0f, 1.0f + __expf(-x));   // inf-safe both ends
}
__device__ __forceinline__ float tanh_fast(float x) {
    float e = __expf(2.0f * x);
    return 1.0f - __fdividef(2.0f, e + 1.0f);     // +-1 at saturation
}
__device__ __forceinline__ v8h pack8(float4 a, float4 b) {   // RNE converts
    v8h r;
    r[0]=(_Float16)a.x; r[1]=(_Float16)a.y; r[2]=(_Float16)a.z; r[3]=(_Float16)a.w;
    r[4]=(_Float16)b.x; r[5]=(_Float16)b.y; r[6]=(_Float16)b.z; r[7]=(_Float16)b.w;
    return r;
}
// select component (c&1,c&2) from A (hf=0) or B (hf=1) per (c&4)
__device__ __forceinline__ float selv(v4f A, v4f B, int c) {
    float a01 = (c & 1) ? A[1] : A[0];
    float a23 = (c & 1) ? A[3] : A[2];
    float av  = (c & 2) ? a23 : a01;
    float b01 = (c & 1) ? B[1] : B[0];
    float b23 = (c & 1) ? B[3] : B[2];
    float bv  = (c & 2) ? b23 : b01;
    return (c & 4) ? bv : av;
}

// ---------------------------------------------------------------------------
// K1a: z[s] = W_exp[pos_ids[s]] @ embs[s] + b_exp  -> xg[s*512 + 0..128)
// ---------------------------------------------------------------------------
__global__ __launch_bounds__(64) void expert_gemv(
    const float* __restrict__ embs, const int* __restrict__ pos_ids,
    const float* __restrict__ W_exp, const float* __restrict__ b_exp,
    float* __restrict__ xg)
{
    __shared__ float Wl[DIM * DIM];          // 64KB, rows XOR-swizzled
    const int e     = blockIdx.x % NEXP;
    const int slice = blockIdx.x / NEXP;     // 0..7
    const int tid   = threadIdx.x;           // 0..63

    const float4* Wg = (const float4*)(W_exp + (size_t)e * DIM * DIM);
    #pragma unroll 4
    for (int it = 0; it < 64; ++it) {
        int idx = it * 64 + tid;             // 0..4095 float4s
        int r = idx >> 5, c4 = idx & 31;
        float4 v = Wg[idx];
        *(float4*)&Wl[r * DIM + (((c4 ^ (r & 31))) << 2)] = v;
    }
    const float b0 = b_exp[e * DIM + tid];
    const float b1 = b_exp[e * DIM + 64 + tid];
    __syncthreads();

    const int r0 = tid, r1 = tid + 64;
    const int sw0 = r0 & 31, sw1 = r1 & 31;
    const int sBeg = slice * 1024, sEnd = sBeg + 1024;
    for (int base = sBeg; base < sEnd; base += 64) {
        int pid = pos_ids[base + tid];
        unsigned long long m = __ballot(pid == e);
        while (m) {
            int t = __builtin_ctzll(m);
            m &= m - 1;
            int s = base + t;
            const float4* ev = (const float4*)(embs + (size_t)s * DIM);
            float a0 = b0, a1 = b1;
            #pragma unroll
            for (int j4 = 0; j4 < 32; ++j4) {
                float4 x  = ev[j4];
                float4 w0 = *(const float4*)&Wl[r0 * DIM + ((j4 ^ sw0) << 2)];
                float4 w1 = *(const float4*)&Wl[r1 * DIM + ((j4 ^ sw1) << 2)];
                a0 = fmaf(w0.x,x.x,fmaf(w0.y,x.y,fmaf(w0.z,x.z,fmaf(w0.w,x.w,a0))));
                a1 = fmaf(w1.x,x.x,fmaf(w1.y,x.y,fmaf(w1.z,x.z,fmaf(w1.w,x.w,a1))));
            }
            float* zp = xg + (size_t)s * NGATE;
            zp[tid]      = a0;
            zp[tid + 64] = a1;
        }
    }
}

// ---------------------------------------------------------------------------
// K1b: gates = W_ih @ z + b_ih + b_hh, stored PERMUTED: xg[s][dim*4 + gate]
// (z read from xg[s*512+0..128) before overwrite)
// ---------------------------------------------------------------------------
__global__ __launch_bounds__(256) void gate_gemm(
    const float* __restrict__ W_ih, const float* __restrict__ b_ih,
    const float* __restrict__ b_hh, float* __restrict__ xg)
{
    __shared__ float zl[32 * DIM];    // 16KB
    __shared__ float Wl[64 * DIM];    // 32KB
    const int tid = threadIdx.x;
    const int s0  = blockIdx.x * 32;

    #pragma unroll
    for (int it = 0; it < 4; ++it) {
        int idx = it * 256 + tid;
        int tok = idx >> 5, c4 = idx & 31;
        float4 v = *(const float4*)(xg + ((size_t)(s0 + tok)) * NGATE + (c4 << 2));
        *(float4*)&zl[tok * DIM + (((c4 ^ (tok & 31))) << 2)] = v;
    }
    __syncthreads();

    const int lane = tid & 63;
    const int tg   = tid >> 6;
    const int swr  = lane & 31;

    for (int ch = 0; ch < 8; ++ch) {
        #pragma unroll
        for (int it = 0; it < 8; ++it) {
            int idx = it * 256 + tid;
            int r = idx >> 5, c4 = idx & 31;
            float4 v = *(const float4*)(W_ih + ((size_t)(ch * 64 + r)) * DIM + (c4 << 2));
            *(float4*)&Wl[r * DIM + ((c4 ^ (r & 31)) << 2)] = v;
        }
        __syncthreads();

        const int row = ch * 64 + lane;      // 0..511
        const float bias = b_ih[row] + b_hh[row];
        float acc[8];
        #pragma unroll
        for (int k = 0; k < 8; ++k) acc[k] = bias;
        #pragma unroll 8
        for (int j4 = 0; j4 < 32; ++j4) {
            float4 w = *(const float4*)&Wl[lane * DIM + ((j4 ^ swr) << 2)];
            #pragma unroll
            for (int k = 0; k < 8; ++k) {
                int tok = tg * 8 + k;
                float4 z = *(const float4*)&zl[tok * DIM + ((j4 ^ (tok & 31)) << 2)];
                acc[k] = fmaf(w.x,z.x,fmaf(w.y,z.y,fmaf(w.z,z.z,fmaf(w.w,z.w,acc[k]))));
            }
        }
        const int pidx = ((row & 127) << 2) + (row >> 7);   // dim*4 + gate
        #pragma unroll
        for (int k = 0; k < 8; ++k) {
            int tok = tg * 8 + k;
            xg[((size_t)(s0 + tok)) * NGATE + pidx] = acc[k];
        }
        __syncthreads();
    }
}

// ---------------------------------------------------------------------------
// K2: MFMA LSTM scan + max-pool. ONE block, 256 threads (4 waves, 1 wave/SIMD).
// Wave g owns dims [32g,32g+32): 8 tiles (gate x half) of 16 rows, K=128 in 4
// chunks of mfma_f32_16x16x32_f16. B columns all = h (fp16, from LDS, double-
// buffered). C layout col=lane&15,row=q*4+reg with identical columns => lane
// (q,c) holds rows q*4+{0..3} of every tile; update lane c<8 selects its dim's
// 4 gate values via cndmask (no LDS, no second barrier).
// ---------------------------------------------------------------------------
__global__ __launch_bounds__(256, 1) void lstm_scan(
    const float* __restrict__ xg, const float* __restrict__ W_hh,
    float* __restrict__ out)
{
    const int T    = threadIdx.x;
    const int wg   = T >> 6;         // wave id: owns dims [32*wg, 32*wg+32)
    const int lane = T & 63;
    const int q    = lane >> 4;      // quad 0..3
    const int c    = lane & 15;      // A row-in-tile; C column
    const int q8   = q * 8;
    const bool upd = (c < 8);        // 32 update lanes per wave (cols 0..7)
    const int d    = wg * 32 + q * 4 + (c & 3) + ((c & 4) ? 16 : 0);

    __shared__ __align__(16) _Float16 hbuf[2][DIM];

    // ---- A-fragments: tile (gate G, half H) rows = G*128 + wg*32 + H*16 + c,
    //      4 K-chunks each; named vars, MFMA-only use -> AGPR-resident ----
#define LOADA(G,H) \
    v8h a##G##H##0, a##G##H##1, a##G##H##2, a##G##H##3; { \
        const float4* p = (const float4*)(W_hh + \
            (size_t)((G) * 128 + wg * 32 + (H) * 16 + c) * DIM) + q * 2; \
        a##G##H##0 = pack8(p[ 0], p[ 1]); \
        a##G##H##1 = pack8(p[ 8], p[ 9]); \
        a##G##H##2 = pack8(p[16], p[17]); \
        a##G##H##3 = pack8(p[24], p[25]); }
    LOADA(0,0) LOADA(0,1) LOADA(1,0) LOADA(1,1)
    LOADA(2,0) LOADA(2,1) LOADA(3,0) LOADA(3,1)
#undef LOADA

    float cst  = 0.0f;
    float hmax = -INFINITY;

    if (upd) hbuf[0][d] = (_Float16)0.0f;    // h_0 = 0
    __syncthreads();                          // once; vmcnt drain harmless here

    // xg prefetch pipeline, distance 4 (raw barriers keep these in flight)
    float4 X0 = {0,0,0,0}, X1 = X0, X2 = X0, X3 = X0;
    if (upd) {
        X0 = *(const float4*)(xg + (size_t)0 * NGATE + 4 * d);
        X1 = *(const float4*)(xg + (size_t)1 * NGATE + 4 * d);
        X2 = *(const float4*)(xg + (size_t)2 * NGATE + 4 * d);
        X3 = *(const float4*)(xg + (size_t)3 * NGATE + 4 * d);
    }

    const v4f Z4 = {0.0f, 0.0f, 0.0f, 0.0f};

#define MFMA4(G,H,B0,B1,B2,B3) \
    __builtin_amdgcn_mfma_f32_16x16x32_f16(a##G##H##3, B3, \
    __builtin_amdgcn_mfma_f32_16x16x32_f16(a##G##H##2, B2, \
    __builtin_amdgcn_mfma_f32_16x16x32_f16(a##G##H##1, B1, \
    __builtin_amdgcn_mfma_f32_16x16x32_f16(a##G##H##0, B0, Z4, 0,0,0), 0,0,0), 0,0,0), 0,0,0)

#define STEP(XV, tp, bf, nbf) { \
    const v8h B0 = *(const v8h*)&hbuf[bf][ 0 + q8]; \
    const v8h B1 = *(const v8h*)&hbuf[bf][32 + q8]; \
    const v8h B2 = *(const v8h*)&hbuf[bf][64 + q8]; \
    const v8h B3 = *(const v8h*)&hbuf[bf][96 + q8]; \
    float4 xcur = XV; \
    if (upd) XV = *(const float4*)(xg + (size_t)(tp) * NGATE + 4 * d); \
    v4f acc00 = MFMA4(0,0,B0,B1,B2,B3); v4f acc01 = MFMA4(0,1,B0,B1,B2,B3); \
    v4f acc10 = MFMA4(1,0,B0,B1,B2,B3); v4f acc11 = MFMA4(1,1,B0,B1,B2,B3); \
    v4f acc20 = MFMA4(2,0,B0,B1,B2,B3); v4f acc21 = MFMA4(2,1,B0,B1,B2,B3); \
    v4f acc30 = MFMA4(3,0,B0,B1,B2,B3); v4f acc31 = MFMA4(3,1,B0,B1,B2,B3); \
    if (upd) { \
        const float pi = selv(acc00, acc01, c) + xcur.x; \
        const float pf = selv(acc10, acc11, c) + xcur.y; \
        const float pg = selv(acc20, acc21, c) + xcur.z; \
        const float po = selv(acc30, acc31, c) + xcur.w; \
        const float iv = sigm_fast(pi); \
        const float fv = sigm_fast(pf); \
        const float gv = tanh_fast(pg); \
        const float ov = sigm_fast(po); \
        cst = fmaf(fv, cst, iv * gv); \
        const float h = ov * tanh_fast(cst); \
        hmax = fmaxf(hmax, h); \
        hbuf[nbf][d] = (_Float16)h; \
    } \
    asm volatile("s_waitcnt lgkmcnt(0)\n\ts_barrier" ::: "memory"); }

    for (int t = 0; t < SEQ; t += 4) {
        const int t4 = (t + 4 < SEQ) ? t + 4 : SEQ - 1;
        const int t5 = (t + 5 < SEQ) ? t + 5 : SEQ - 1;
        const int t6 = (t + 6 < SEQ) ? t + 6 : SEQ - 1;
        const int t7 = (t + 7 < SEQ) ? t + 7 : SEQ - 1;
        STEP(X0, t4, 0, 1)
        STEP(X1, t5, 1, 0)
        STEP(X2, t6, 0, 1)
        STEP(X3, t7, 1, 0)
    }
#undef STEP
#undef MFMA4

    if (upd) out[d] = hmax;   // out[1][128]
}

// ---------------------------------------------------------------------------
extern "C" void kernel_launch(void* const* d_in, const int* in_sizes, int n_in,
                              void* d_out, int out_size, void* d_ws, size_t ws_size,
                              hipStream_t stream)
{
    const float* embs  = (const float*)d_in[0];
    const int*   pos   = (const int*)  d_in[1];
    const float* W_exp = (const float*)d_in[2];
    const float* b_exp = (const float*)d_in[3];
    const float* W_ih  = (const float*)d_in[4];
    const float* W_hh  = (const float*)d_in[5];
    const float* b_ih  = (const float*)d_in[6];
    const float* b_hh  = (const float*)d_in[7];
    float* out = (float*)d_out;
    float* xg  = (float*)d_ws;   // [SEQ][512] fp32 = 16 MB

    expert_gemv<<<dim3(NEXP * 8), 64, 0, stream>>>(embs, pos, W_exp, b_exp, xg);
    gate_gemm  <<<dim3(256), 256, 0, stream>>>(W_ih, b_ih, b_hh, xg);
    lstm_scan  <<<dim3(1), 256, 0, stream>>>(xg, W_hh, out);
}

// Round 6
// 5011.934 us; speedup vs baseline: 1.3395x; 1.0044x over previous
//
#include <hip/hip_runtime.h>
#include <math.h>

// POSTagEncoder: expert-routed linear -> 1-layer LSTM (i,f,g,o) -> time max-pool.
// S=8192, D=128, E=48. Output [1,128] fp32.
//
// Round-6 scan change: K-MAJOR MFMA INTERLEAVE. Round-5 counters (MfmaUtil
// 0.140% GPU = 36% of the active CU = ~507 cyc/step for 32 MFMAs) proved the
// nested per-tile chains ran at dependent-chain latency (~16 cyc/MFMA), not
// issue rate (~4.8). This version issues the 32 MFMAs k-chunk-major across the
// 8 accumulators (dependent reuse distance = 8 instrs > MFMA latency).
// Everything else (raw lgkmcnt-only barrier, per-wave dim ownership with
// in-register cndmask gate select, [t][dim][gate] xg layout with distance-4
// prefetch) is retained from round 5 -- it all verified.

#define SEQ   8192
#define DIM   128
#define NGATE 512
#define NEXP  48

typedef _Float16 v8h  __attribute__((ext_vector_type(8)));
typedef float    v4f  __attribute__((ext_vector_type(4)));

__device__ __forceinline__ float sigm_fast(float x) {
    return __fdividef(1.0f, 1.0f + __expf(-x));   // inf-safe both ends
}
__device__ __forceinline__ float tanh_fast(float x) {
    float e = __expf(2.0f * x);
    return 1.0f - __fdividef(2.0f, e + 1.0f);     // +-1 at saturation
}
__device__ __forceinline__ v8h pack8(float4 a, float4 b) {   // RNE converts
    v8h r;
    r[0]=(_Float16)a.x; r[1]=(_Float16)a.y; r[2]=(_Float16)a.z; r[3]=(_Float16)a.w;
    r[4]=(_Float16)b.x; r[5]=(_Float16)b.y; r[6]=(_Float16)b.z; r[7]=(_Float16)b.w;
    return r;
}
// select component (c&1,c&2) from A (half 0) or B (half 1) per (c&4)
__device__ __forceinline__ float selv(v4f A, v4f B, int c) {
    float a01 = (c & 1) ? A[1] : A[0];
    float a23 = (c & 1) ? A[3] : A[2];
    float av  = (c & 2) ? a23 : a01;
    float b01 = (c & 1) ? B[1] : B[0];
    float b23 = (c & 1) ? B[3] : B[2];
    float bv  = (c & 2) ? b23 : b01;
    return (c & 4) ? bv : av;
}

// ---------------------------------------------------------------------------
// K1a: z[s] = W_exp[pos_ids[s]] @ embs[s] + b_exp  -> xg[s*512 + 0..128)
// ---------------------------------------------------------------------------
__global__ __launch_bounds__(64) void expert_gemv(
    const float* __restrict__ embs, const int* __restrict__ pos_ids,
    const float* __restrict__ W_exp, const float* __restrict__ b_exp,
    float* __restrict__ xg)
{
    __shared__ float Wl[DIM * DIM];          // 64KB, rows XOR-swizzled
    const int e     = blockIdx.x % NEXP;
    const int slice = blockIdx.x / NEXP;     // 0..7
    const int tid   = threadIdx.x;           // 0..63

    const float4* Wg = (const float4*)(W_exp + (size_t)e * DIM * DIM);
    #pragma unroll 4
    for (int it = 0; it < 64; ++it) {
        int idx = it * 64 + tid;             // 0..4095 float4s
        int r = idx >> 5, c4 = idx & 31;
        float4 v = Wg[idx];
        *(float4*)&Wl[r * DIM + (((c4 ^ (r & 31))) << 2)] = v;
    }
    const float b0 = b_exp[e * DIM + tid];
    const float b1 = b_exp[e * DIM + 64 + tid];
    __syncthreads();

    const int r0 = tid, r1 = tid + 64;
    const int sw0 = r0 & 31, sw1 = r1 & 31;
    const int sBeg = slice * 1024, sEnd = sBeg + 1024;
    for (int base = sBeg; base < sEnd; base += 64) {
        int pid = pos_ids[base + tid];
        unsigned long long m = __ballot(pid == e);
        while (m) {
            int t = __builtin_ctzll(m);
            m &= m - 1;
            int s = base + t;
            const float4* ev = (const float4*)(embs + (size_t)s * DIM);
            float a0 = b0, a1 = b1;
            #pragma unroll
            for (int j4 = 0; j4 < 32; ++j4) {
                float4 x  = ev[j4];
                float4 w0 = *(const float4*)&Wl[r0 * DIM + ((j4 ^ sw0) << 2)];
                float4 w1 = *(const float4*)&Wl[r1 * DIM + ((j4 ^ sw1) << 2)];
                a0 = fmaf(w0.x,x.x,fmaf(w0.y,x.y,fmaf(w0.z,x.z,fmaf(w0.w,x.w,a0))));
                a1 = fmaf(w1.x,x.x,fmaf(w1.y,x.y,fmaf(w1.z,x.z,fmaf(w1.w,x.w,a1))));
            }
            float* zp = xg + (size_t)s * NGATE;
            zp[tid]      = a0;
            zp[tid + 64] = a1;
        }
    }
}

// ---------------------------------------------------------------------------
// K1b: gates = W_ih @ z + b_ih + b_hh, stored PERMUTED: xg[s][dim*4 + gate]
// ---------------------------------------------------------------------------
__global__ __launch_bounds__(256) void gate_gemm(
    const float* __restrict__ W_ih, const float* __restrict__ b_ih,
    const float* __restrict__ b_hh, float* __restrict__ xg)
{
    __shared__ float zl[32 * DIM];    // 16KB
    __shared__ float Wl[64 * DIM];    // 32KB
    const int tid = threadIdx.x;
    const int s0  = blockIdx.x * 32;

    #pragma unroll
    for (int it = 0; it < 4; ++it) {
        int idx = it * 256 + tid;
        int tok = idx >> 5, c4 = idx & 31;
        float4 v = *(const float4*)(xg + ((size_t)(s0 + tok)) * NGATE + (c4 << 2));
        *(float4*)&zl[tok * DIM + (((c4 ^ (tok & 31))) << 2)] = v;
    }
    __syncthreads();

    const int lane = tid & 63;
    const int tg   = tid >> 6;
    const int swr  = lane & 31;

    for (int ch = 0; ch < 8; ++ch) {
        #pragma unroll
        for (int it = 0; it < 8; ++it) {
            int idx = it * 256 + tid;
            int r = idx >> 5, c4 = idx & 31;
            float4 v = *(const float4*)(W_ih + ((size_t)(ch * 64 + r)) * DIM + (c4 << 2));
            *(float4*)&Wl[r * DIM + ((c4 ^ (r & 31)) << 2)] = v;
        }
        __syncthreads();

        const int row = ch * 64 + lane;      // 0..511
        const float bias = b_ih[row] + b_hh[row];
        float acc[8];
        #pragma unroll
        for (int k = 0; k < 8; ++k) acc[k] = bias;
        #pragma unroll 8
        for (int j4 = 0; j4 < 32; ++j4) {
            float4 w = *(const float4*)&Wl[lane * DIM + ((j4 ^ swr) << 2)];
            #pragma unroll
            for (int k = 0; k < 8; ++k) {
                int tok = tg * 8 + k;
                float4 z = *(const float4*)&zl[tok * DIM + ((j4 ^ (tok & 31)) << 2)];
                acc[k] = fmaf(w.x,z.x,fmaf(w.y,z.y,fmaf(w.z,z.z,fmaf(w.w,z.w,acc[k]))));
            }
        }
        const int pidx = ((row & 127) << 2) + (row >> 7);   // dim*4 + gate
        #pragma unroll
        for (int k = 0; k < 8; ++k) {
            int tok = tg * 8 + k;
            xg[((size_t)(s0 + tok)) * NGATE + pidx] = acc[k];
        }
        __syncthreads();
    }
}

// ---------------------------------------------------------------------------
// K2: MFMA LSTM scan + max-pool. ONE block, 256 threads (4 waves, 1 wave/SIMD).
// Wave wg owns dims [32wg,32wg+32): 8 tiles (gate x half) of 16 rows, K=128 in
// 4 chunks of mfma_f32_16x16x32_f16 issued K-MAJOR (8 independent MFMAs between
// dependent accumulator reuses).
// ---------------------------------------------------------------------------
__global__ __launch_bounds__(256, 1) void lstm_scan(
    const float* __restrict__ xg, const float* __restrict__ W_hh,
    float* __restrict__ out)
{
    const int T    = threadIdx.x;
    const int wg   = T >> 6;         // wave id: owns dims [32*wg, 32*wg+32)
    const int lane = T & 63;
    const int q    = lane >> 4;      // quad 0..3
    const int c    = lane & 15;      // A row-in-tile; C column
    const int q8   = q * 8;
    const bool upd = (c < 8);        // 32 update lanes per wave (cols 0..7)
    const int d    = wg * 32 + q * 4 + (c & 3) + ((c & 4) ? 16 : 0);

    __shared__ __align__(16) _Float16 hbuf[2][DIM];

    // ---- A-fragments: tile (gate G, half H) rows = G*128 + wg*32 + H*16 + c,
    //      4 K-chunks each; named vars, MFMA-only use -> AGPR-resident ----
#define LOADA(G,H) \
    v8h a##G##H##0, a##G##H##1, a##G##H##2, a##G##H##3; { \
        const float4* p = (const float4*)(W_hh + \
            (size_t)((G) * 128 + wg * 32 + (H) * 16 + c) * DIM) + q * 2; \
        a##G##H##0 = pack8(p[ 0], p[ 1]); \
        a##G##H##1 = pack8(p[ 8], p[ 9]); \
        a##G##H##2 = pack8(p[16], p[17]); \
        a##G##H##3 = pack8(p[24], p[25]); }
    LOADA(0,0) LOADA(0,1) LOADA(1,0) LOADA(1,1)
    LOADA(2,0) LOADA(2,1) LOADA(3,0) LOADA(3,1)
#undef LOADA

    float cst  = 0.0f;
    float hmax = -INFINITY;

    if (upd) hbuf[0][d] = (_Float16)0.0f;    // h_0 = 0
    __syncthreads();                          // once; vmcnt drain harmless here

    // xg prefetch pipeline, distance 4 (raw barriers keep these in flight)
    float4 X0 = {0,0,0,0}, X1 = X0, X2 = X0, X3 = X0;
    if (upd) {
        X0 = *(const float4*)(xg + (size_t)0 * NGATE + 4 * d);
        X1 = *(const float4*)(xg + (size_t)1 * NGATE + 4 * d);
        X2 = *(const float4*)(xg + (size_t)2 * NGATE + 4 * d);
        X3 = *(const float4*)(xg + (size_t)3 * NGATE + 4 * d);
    }

    const v4f Z4 = {0.0f, 0.0f, 0.0f, 0.0f};

#define MF(G,H,K,B,CIN) __builtin_amdgcn_mfma_f32_16x16x32_f16(a##G##H##K, B, CIN, 0, 0, 0)

#define STEP(XV, tp, bf, nbf) { \
    const v8h B0 = *(const v8h*)&hbuf[bf][ 0 + q8]; \
    const v8h B1 = *(const v8h*)&hbuf[bf][32 + q8]; \
    const v8h B2 = *(const v8h*)&hbuf[bf][64 + q8]; \
    const v8h B3 = *(const v8h*)&hbuf[bf][96 + q8]; \
    float4 xcur = XV; \
    if (upd) XV = *(const float4*)(xg + (size_t)(tp) * NGATE + 4 * d); \
    /* K-chunk 0 (from Z4): 8 independent MFMAs */ \
    v4f c00 = MF(0,0,0,B0,Z4);  v4f c01 = MF(0,1,0,B0,Z4); \
    v4f c10 = MF(1,0,0,B0,Z4);  v4f c11 = MF(1,1,0,B0,Z4); \
    v4f c20 = MF(2,0,0,B0,Z4);  v4f c21 = MF(2,1,0,B0,Z4); \
    v4f c30 = MF(3,0,0,B0,Z4);  v4f c31 = MF(3,1,0,B0,Z4); \
    /* K-chunk 1 */ \
    c00 = MF(0,0,1,B1,c00);  c01 = MF(0,1,1,B1,c01); \
    c10 = MF(1,0,1,B1,c10);  c11 = MF(1,1,1,B1,c11); \
    c20 = MF(2,0,1,B1,c20);  c21 = MF(2,1,1,B1,c21); \
    c30 = MF(3,0,1,B1,c30);  c31 = MF(3,1,1,B1,c31); \
    /* K-chunk 2 */ \
    c00 = MF(0,0,2,B2,c00);  c01 = MF(0,1,2,B2,c01); \
    c10 = MF(1,0,2,B2,c10);  c11 = MF(1,1,2,B2,c11); \
    c20 = MF(2,0,2,B2,c20);  c21 = MF(2,1,2,B2,c21); \
    c30 = MF(3,0,2,B2,c30);  c31 = MF(3,1,2,B2,c31); \
    /* K-chunk 3 */ \
    c00 = MF(0,0,3,B3,c00);  c01 = MF(0,1,3,B3,c01); \
    c10 = MF(1,0,3,B3,c10);  c11 = MF(1,1,3,B3,c11); \
    c20 = MF(2,0,3,B3,c20);  c21 = MF(2,1,3,B3,c21); \
    c30 = MF(3,0,3,B3,c30);  c31 = MF(3,1,3,B3,c31); \
    if (upd) { \
        const float pi = selv(c00, c01, c) + xcur.x; \
        const float pf = selv(c10, c11, c) + xcur.y; \
        const float pg = selv(c20, c21, c) + xcur.z; \
        const float po = selv(c30, c31, c) + xcur.w; \
        const float iv = sigm_fast(pi); \
        const float fv = sigm_fast(pf); \
        const float gv = tanh_fast(pg); \
        const float ov = sigm_fast(po); \
        cst = fmaf(fv, cst, iv * gv); \
        const float h = ov * tanh_fast(cst); \
        hmax = fmaxf(hmax, h); \
        hbuf[nbf][d] = (_Float16)h; \
    } \
    asm volatile("s_waitcnt lgkmcnt(0)\n\ts_barrier" ::: "memory"); }

    for (int t = 0; t < SEQ; t += 4) {
        const int t4 = (t + 4 < SEQ) ? t + 4 : SEQ - 1;
        const int t5 = (t + 5 < SEQ) ? t + 5 : SEQ - 1;
        const int t6 = (t + 6 < SEQ) ? t + 6 : SEQ - 1;
        const int t7 = (t + 7 < SEQ) ? t + 7 : SEQ - 1;
        STEP(X0, t4, 0, 1)
        STEP(X1, t5, 1, 0)
        STEP(X2, t6, 0, 1)
        STEP(X3, t7, 1, 0)
    }
#undef STEP
#undef MF

    if (upd) out[d] = hmax;   // out[1][128]
}

// ---------------------------------------------------------------------------
extern "C" void kernel_launch(void* const* d_in, const int* in_sizes, int n_in,
                              void* d_out, int out_size, void* d_ws, size_t ws_size,
                              hipStream_t stream)
{
    const float* embs  = (const float*)d_in[0];
    const int*   pos   = (const int*)  d_in[1];
    const float* W_exp = (const float*)d_in[2];
    const float* b_exp = (const float*)d_in[3];
    const float* W_ih  = (const float*)d_in[4];
    const float* W_hh  = (const float*)d_in[5];
    const float* b_ih  = (const float*)d_in[6];
    const float* b_hh  = (const float*)d_in[7];
    float* out = (float*)d_out;
    float* xg  = (float*)d_ws;   // [SEQ][512] fp32 = 16 MB

    expert_gemv<<<dim3(NEXP * 8), 64, 0, stream>>>(embs, pos, W_exp, b_exp, xg);
    gate_gemm  <<<dim3(256), 256, 0, stream>>>(W_ih, b_ih, b_hh, xg);
    lstm_scan  <<<dim3(1), 256, 0, stream>>>(xg, W_hh, out);
}